// Round 1
// 160.554 us; speedup vs baseline: 1.0018x; 1.0018x over previous
//
#include <hip/hip_runtime.h>

// WindowOverlapProcessor — gather, one thread per output pixel.
//
// Structure unchanged from the 160.8-us version (dense per-wave dwordx3
// gathers; each input triple read exactly once; 97.5 MB in + 25.2 MB out
// -> ~18-20 us BW floor for the kernel dispatch itself). This revision
// strips everything that is NOT the 4 gather loads + 3 plane stores:
//   - blend weights closed-form (sigma=4 gaussian, normalizer 1/S with
//     S = 9.5759316 precomputed) -> no LDS, no __syncthreads, no serial
//     tid==0 normalize preamble per block
//   - h/b derived from blockIdx only -> whole vertical index/weight
//     chain is provably wave-uniform (SALU), lanes only do the w side
//   - int32 element offsets (max byte offset 97.5 MB < 2^31) -> SGPR
//     base + 32-bit voffset addressing instead of per-lane 64-bit
//     address chains (was 21 v_lshl_add_u64)
//   - __expf + v_rcp instead of libm expf and the IEEE divide sequence
//   - nontemporal stores: output is write-once; keep L2 for the input
//     lines that are split across the p10/p11 loads of a wave

#define OH 512
#define OW 512
#define NB 8
#define NC 3
#define STR 8
#define HWIN 63
#define NWIN (HWIN * HWIN)
#define PLANE (OH * OW)

struct F3 { float x, y, z; };

// g[d] = exp(-(d-7.5)^2/32) / S,  S = sum_{i<16} exp(-(i-7.5)^2/32) = 9.5759316
__device__ __forceinline__ float gblend(int d) {
    const float x = (float)d - 7.5f;
    return __expf(-(x * x) * 0.03125f) * 0.10442840f;
}

__global__ __launch_bounds__(512) void window_overlap_kernel(
    const float* __restrict__ win, float* __restrict__ out) {
    const int w = threadIdx.x;                 // lane -> pixel column
    const int h = blockIdx.x & (OH - 1);       // block-uniform -> SALU
    const int b = blockIdx.x >> 9;

    // vertical covering windows: i1 always valid; i0 = i1-1 weight-zeroed
    // at the top border; rows h>=504 covered only by window 62's bottom
    // half (dh1 in [8,16) -> gh0 = 0). All of this is wave-uniform.
    const int i1 = min(h >> 3, HWIN - 1);
    const int dh1 = h - i1 * STR;                 // [0,16)
    const int i0 = max(i1 - 1, 0);
    const int dh0 = (dh1 <= 7) ? dh1 + 8 : dh1;   // always a valid row of i0

    // horizontal covering windows (per-lane), same structure
    const int j1 = min(w >> 3, HWIN - 1);
    const int dw1 = w - j1 * STR;
    const int j0 = max(j1 - 1, 0);
    const int dw0 = (dw1 <= 7) ? dw1 + 8 : dw1;

    // 4 covering triples; loads issued before the weight math so the
    // __expf chain overlaps the gathers in flight
    const F3* __restrict__ wp = (const F3*)win;
    const int r0 = (b * NWIN + i0 * HWIN) * 256 + dh0 * 16;
    const int r1 = (b * NWIN + i1 * HWIN) * 256 + dh1 * 16;
    const F3 v00 = wp[r0 + j0 * 256 + dw0];
    const F3 v01 = wp[r0 + j1 * 256 + dw1];
    const F3 v10 = wp[r1 + j0 * 256 + dw0];
    const F3 v11 = wp[r1 + j1 * 256 + dw1];

    const float gh1 = gblend(dh1);
    const float gh0 = (i1 >= 1 && dh1 <= 7) ? gblend(dh0) : 0.0f;
    const float gw1 = gblend(dw1);
    const float gw0 = (j1 >= 1 && dw1 <= 7) ? gblend(dw0) : 0.0f;

    // separable denominator; rcp is ~1 ulp, denom in [3.2e-4, 0.19]
    const float r = __builtin_amdgcn_rcpf((gh0 + gh1) * (gw0 + gw1) + 1e-8f);

    const float ax = gh0 * (gw0 * v00.x + gw1 * v01.x) + gh1 * (gw0 * v10.x + gw1 * v11.x);
    const float ay = gh0 * (gw0 * v00.y + gw1 * v01.y) + gh1 * (gw0 * v10.y + gw1 * v11.y);
    const float az = gh0 * (gw0 * v00.z + gw1 * v01.z) + gh1 * (gw0 * v10.z + gw1 * v11.z);

    const int p = b * (NC * PLANE) + h * OW + w;
    __builtin_nontemporal_store(ax * r, &out[p]);
    __builtin_nontemporal_store(ay * r, &out[p + PLANE]);
    __builtin_nontemporal_store(az * r, &out[p + 2 * PLANE]);
}

extern "C" void kernel_launch(void* const* d_in, const int* in_sizes, int n_in,
                              void* d_out, int out_size, void* d_ws, size_t ws_size,
                              hipStream_t stream) {
    const float* windows = (const float*)d_in[0];
    float* out = (float*)d_out;
    // one block per (b, h) row: 4096 blocks x 512 threads = 2,097,152 px
    window_overlap_kernel<<<NB * OH, 512, 0, stream>>>(windows, out);
}